// Round 3
// baseline (122.128 us; speedup 1.0000x reference)
//
#include <hip/hip_runtime.h>
#include <cstdint>

#define NEMB   512     // codebook entries
#define DQ     64      // quantized vector dim (in_mem*out_mem)
#define NROWS  4096    // in_g*out_g weight rows
#define BATCH  8192
#define KDIM   512     // in_g*in_mem
#define NDIM   512     // out_g*out_mem

#define CONV_BLOCKS 2048
#define VQ_BLOCKS   256    // 16 rows each

typedef __attribute__((ext_vector_type(8))) short bf16x8;
typedef __attribute__((ext_vector_type(4))) float floatx4;

__device__ __forceinline__ unsigned short f2bf(float f) {
    unsigned int u = __float_as_uint(f);
    u += 0x7fffu + ((u >> 16) & 1u);     // RNE
    return (unsigned short)(u >> 16);
}

__device__ __forceinline__ void async16(const void* g, void* l) {
    __builtin_amdgcn_global_load_lds(
        (const __attribute__((address_space(1))) void*)g,
        (__attribute__((address_space(3))) void*)l, 16, 0, 0);
}

// ---------------------------------------------------------------------------
// Kernel 1 (fused): blocks [0,2048) convert x fp32->bf16; blocks [2048,2304)
// do VQ argmin (f64, inline candidate norms) + W^T bf16 + diff partials.
// No e2 dependency, no atomics: partial diff per vq-block -> ws.
// ---------------------------------------------------------------------------
__global__ __launch_bounds__(256) void fused_prep_vq(
    const float* __restrict__ x,        // [8192*512]
    const float* __restrict__ weight,   // [4096][64]
    const float* __restrict__ embed,    // [64][512]
    unsigned short* __restrict__ xb,    // bf16 out [8192*512]
    unsigned short* __restrict__ wt,    // bf16 W^T [512][512]  (wt[n][k])
    float* __restrict__ partials,       // [256] diff partial sums
    const int* __restrict__ use_qw)
{
    const int t   = threadIdx.x;
    const int bid = blockIdx.x;

    if (bid < CONV_BLOCKS) {            // ---- x conversion ----
        const int gid = bid * 256 + t;
#pragma unroll
        for (int it = 0; it < 2; ++it) {
            const int idx = gid + it * 524288;        // float4 index < 1048576
            float4 v = reinterpret_cast<const float4*>(x)[idx];
            ushort4 o;
            o.x = f2bf(v.x); o.y = f2bf(v.y); o.z = f2bf(v.z); o.w = f2bf(v.w);
            reinterpret_cast<ushort4*>(xb)[idx] = o;
        }
        return;
    }

    // ---- VQ part ----
    const int vb   = bid - CONV_BLOCKS;  // 0..255
    const int wave = t >> 6;
    const int lane = t & 63;
    const int rblk = vb * 16;
    const bool qon = (use_qw[0] != 0);

    __shared__ float wlds[16 * 64];      // 4 KB: block's 16 weight rows
    __shared__ int   bidx_lds[16];
    __shared__ float red[4];

    reinterpret_cast<float4*>(wlds)[t] =
        reinterpret_cast<const float4*>(weight + (size_t)rblk * 64)[t];
    __syncthreads();

    if (qon) {
        const int j0 = lane * 8;         // this lane's 8 contiguous candidates
        const int rw = wave * 4;         // wave's first local row

        double acc[4][8];
        double ee[8];
#pragma unroll
        for (int c = 0; c < 8; ++c) ee[c] = 0.0;
#pragma unroll
        for (int r = 0; r < 4; ++r)
#pragma unroll
            for (int c = 0; c < 8; ++c) acc[r][c] = 0.0;

        for (int d = 0; d < DQ; ++d) {
            const float4 ea = *reinterpret_cast<const float4*>(embed + d * NEMB + j0);
            const float4 eb = *reinterpret_cast<const float4*>(embed + d * NEMB + j0 + 4);
            double ev[8];
            ev[0] = (double)ea.x; ev[1] = (double)ea.y; ev[2] = (double)ea.z; ev[3] = (double)ea.w;
            ev[4] = (double)eb.x; ev[5] = (double)eb.y; ev[6] = (double)eb.z; ev[7] = (double)eb.w;
#pragma unroll
            for (int c = 0; c < 8; ++c) ee[c] = fma(ev[c], ev[c], ee[c]);
#pragma unroll
            for (int r = 0; r < 4; ++r) {
                const double wv = (double)wlds[(rw + r) * 64 + d];   // LDS broadcast
#pragma unroll
                for (int c = 0; c < 8; ++c)
                    acc[r][c] = fma(wv, ev[c], acc[r][c]);
            }
        }

#pragma unroll
        for (int r = 0; r < 4; ++r) {
            double best = 1e300;
            int bi = 0;
#pragma unroll
            for (int c = 0; c < 8; ++c) {
                const double q = fma(-2.0, acc[r][c], ee[c]);
                if (q < best) { best = q; bi = j0 + c; }   // ascending j: strict < keeps lowest idx
            }
#pragma unroll
            for (int off = 1; off < 64; off <<= 1) {
                const double ob = __shfl_xor(best, off, 64);
                const int    oi = __shfl_xor(bi,   off, 64);
                if (ob < best || (ob == best && oi < bi)) { best = ob; bi = oi; }
            }
            if (lane == 0) bidx_lds[rw + r] = bi;
        }
    }
    __syncthreads();

    // ---- write phase: 128 threads; thread = (row, om); 16 B coalesced store ----
    float dsum = 0.f;
    if (t < 128) {
        const int rloc = t >> 3, om = t & 7;
        const int row = rblk + rloc;
        const int g = row >> 6, og = row & 63;
        const int bidx = qon ? bidx_lds[rloc] : 0;
        alignas(16) unsigned short q8[8];
#pragma unroll
        for (int i = 0; i < 8; ++i) {
            const int d = i * 8 + om;
            const float wv = wlds[rloc * 64 + d];
            float qv;
            if (qon) {
                qv = embed[d * NEMB + bidx];
                const float df = qv - wv;
                dsum = fmaf(df, df, dsum);
            } else {
                qv = wv;
            }
            q8[i] = f2bf(qv);
        }
        // W[k = g*8+i][n = og*8+om] -> wt[n*KDIM + k]; 8 consecutive k = 16 B
        *reinterpret_cast<int4*>(wt + (size_t)(og * 8 + om) * KDIM + g * 8) =
            *reinterpret_cast<const int4*>(q8);
    }

#pragma unroll
    for (int off = 32; off > 0; off >>= 1) dsum += __shfl_down(dsum, off, 64);
    if (lane == 0) red[wave] = dsum;
    __syncthreads();
    if (t == 0) partials[vb] = red[0] + red[1] + red[2] + red[3];
}

// ---------------------------------------------------------------------------
// Kernel 2: res = xb[8192,512] @ wt^T   (wt stored [N][K])
// 64x64 tile, BK=32, 4 waves in 2x2 (each 32x32), grid 1024 = 4 blocks/CU.
// XCD swizzle: all 8 n-tiles of an m-stripe land on one XCD (A L2-resident).
// Block 0 additionally reduces the 256 diff partials.
// ---------------------------------------------------------------------------
__global__ __launch_bounds__(256, 4) void gemm_kernel(
    const unsigned short* __restrict__ xb,   // bf16 [8192][512]
    const unsigned short* __restrict__ wt,   // bf16 [512][512]
    float* __restrict__ out,                 // fp32 [8192][512]
    const float* __restrict__ partials,      // [256]
    float* diff_slot)
{
    __shared__ unsigned short As[64 * 32];   // 4 KB [m][k]
    __shared__ unsigned short Bs[64 * 32];   // 4 KB [n][k]

    const int tid  = threadIdx.x;
    const int wave = tid >> 6;
    const int lane = tid & 63;

    // swizzle: flat -> (xcd, m-tile, n-tile); XCD = flat%8 (round-robin heuristic)
    const int flat = blockIdx.x;             // 0..1023
    const int xcd  = flat & 7;
    const int idx  = flat >> 3;              // 0..127
    const int mt   = xcd * 16 + (idx >> 3);  // 0..127
    const int nt   = idx & 7;                // 0..7
    const int m0 = mt * 64;
    const int n0 = nt * 64;
    const int wm = (wave >> 1) * 32;
    const int wn = (wave & 1) * 32;

    const int srow = lane >> 2;              // staging row within 16-row chunk
    const int scol = (lane & 3) * 8;         // staging k offset (elements)
    const int mrow = lane & 15;              // fragment row
    const int koff = (lane >> 4) * 8;        // fragment k offset

    floatx4 acc[2][2] = {};

    for (int k0 = 0; k0 < KDIM; k0 += 32) {
        __syncthreads();
        {   // each wave stages 16 rows of A and 16 rows of B (1 KB each)
            const int row = wave * 16 + srow;
            async16(xb + (size_t)(m0 + row) * KDIM + k0 + scol, (char*)As + wave * 1024);
            async16(wt + (size_t)(n0 + row) * KDIM + k0 + scol, (char*)Bs + wave * 1024);
        }
        __syncthreads();

        bf16x8 a[2], b[2];
#pragma unroll
        for (int i = 0; i < 2; ++i)
            a[i] = *reinterpret_cast<const bf16x8*>(&As[(wm + i * 16 + mrow) * 32 + koff]);
#pragma unroll
        for (int j = 0; j < 2; ++j)
            b[j] = *reinterpret_cast<const bf16x8*>(&Bs[(wn + j * 16 + mrow) * 32 + koff]);
#pragma unroll
        for (int i = 0; i < 2; ++i)
#pragma unroll
            for (int j = 0; j < 2; ++j)
                acc[i][j] = __builtin_amdgcn_mfma_f32_16x16x32_bf16(a[i], b[j], acc[i][j], 0, 0, 0);
    }

    // C/D layout: col = lane&15, row = (lane>>4)*4 + reg  (m89-verified)
    const int col = lane & 15;
    const int rbase = (lane >> 4) * 4;
#pragma unroll
    for (int i = 0; i < 2; ++i)
#pragma unroll
        for (int j = 0; j < 2; ++j)
#pragma unroll
            for (int r = 0; r < 4; ++r) {
                const int mm = m0 + wm + i * 16 + rbase + r;
                const int nn = n0 + wn + j * 16 + col;
                out[(size_t)mm * NDIM + nn] = acc[i][j][r];
            }

    // diff reduction (one wave of one block)
    if (flat == 0 && wave == 0 && diff_slot) {
        float s = partials[lane] + partials[lane + 64]
                + partials[lane + 128] + partials[lane + 192];
#pragma unroll
        for (int off = 32; off > 0; off >>= 1) s += __shfl_down(s, off, 64);
        if (lane == 0) diff_slot[0] = s * (1.f / (NROWS * DQ));
    }
}

// ---------------------------------------------------------------------------
extern "C" void kernel_launch(void* const* d_in, const int* in_sizes, int n_in,
                              void* d_out, int out_size, void* d_ws, size_t ws_size,
                              hipStream_t stream)
{
    const float* x      = (const float*)d_in[0];
    const float* weight = (const float*)d_in[1];
    const float* embed  = (const float*)d_in[2];
    const int*   use_qw = (const int*)d_in[3];
    float* out = (float*)d_out;

    // ws layout: [0,512K) W^T bf16 ; [512K,513K) diff partials ; [1M,9M) x bf16
    unsigned short* wt   = (unsigned short*)d_ws;
    float* partials      = (float*)((char*)d_ws + (512u << 10));
    unsigned short* xb   = (unsigned short*)((char*)d_ws + (1u << 20));

    float* diff_slot = (out_size > BATCH * NDIM) ? (out + (size_t)BATCH * NDIM) : nullptr;

    fused_prep_vq<<<CONV_BLOCKS + VQ_BLOCKS, 256, 0, stream>>>(
        x, weight, embed, xb, wt, partials, use_qw);
    gemm_kernel<<<1024, 256, 0, stream>>>(xb, wt, out, partials, diff_slot);
}

// Round 4
// 100.025 us; speedup vs baseline: 1.2210x; 1.2210x over previous
//
#include <hip/hip_runtime.h>
#include <cstdint>

#define NEMB   512     // codebook entries
#define DQ     64      // quantized vector dim (in_mem*out_mem)
#define NROWS  4096    // in_g*out_g weight rows
#define BATCH  8192
#define KDIM   512     // in_g*in_mem
#define NDIM   512     // out_g*out_mem

#define VQ_BLOCKS   512    // 8 weight rows each; FIRST in grid (co-schedule w/ conv)
#define CONV_BLOCKS 2048

typedef __attribute__((ext_vector_type(8))) short bf16x8;
typedef __attribute__((ext_vector_type(4))) float floatx4;

__device__ __forceinline__ unsigned short f2bf(float f) {
    unsigned int u = __float_as_uint(f);
    u += 0x7fffu + ((u >> 16) & 1u);     // RNE
    return (unsigned short)(u >> 16);
}

__device__ __forceinline__ void async16(const void* g, void* l) {
    __builtin_amdgcn_global_load_lds(
        (const __attribute__((address_space(1))) void*)g,
        (__attribute__((address_space(3))) void*)l, 16, 0, 0);
}

// ---------------------------------------------------------------------------
// Kernel 1 (fused): blocks [0,512) = VQ (8 rows each); blocks [512,2560) =
// x fp32->bf16 conversion. VQ per-thread state sized to FIT REGISTERS:
// acc[2][8] f64 = 32 VGPRs (R2/R3 spilled acc[4][8]=64 VGPRs -> scratch).
// Candidate norms e2 computed once per block into LDS (removes 8 ee chains).
// ---------------------------------------------------------------------------
__global__ __launch_bounds__(256) void fused_prep_vq(
    const float* __restrict__ x,        // [8192*512]
    const float* __restrict__ weight,   // [4096][64]
    const float* __restrict__ embed,    // [64][512]
    unsigned short* __restrict__ xb,    // bf16 out [8192*512]
    unsigned short* __restrict__ wt,    // bf16 W^T [512][512]  (wt[n][k])
    float* __restrict__ partials,       // [512] diff partial sums
    const int* __restrict__ use_qw)
{
    const int t   = threadIdx.x;
    const int bid = blockIdx.x;

    if (bid >= VQ_BLOCKS) {             // ---- x conversion ----
        const int gid = (bid - VQ_BLOCKS) * 256 + t;
#pragma unroll
        for (int it = 0; it < 2; ++it) {
            const int idx = gid + it * 524288;        // float4 index < 1048576
            float4 v = reinterpret_cast<const float4*>(x)[idx];
            ushort4 o;
            o.x = f2bf(v.x); o.y = f2bf(v.y); o.z = f2bf(v.z); o.w = f2bf(v.w);
            reinterpret_cast<ushort4*>(xb)[idx] = o;
        }
        return;
    }

    // ---- VQ part: 8 rows, 4 waves, 2 rows/wave, 8 candidates/lane ----
    const int wave = t >> 6;
    const int lane = t & 63;
    const int rblk = bid * 8;
    const bool qon = (use_qw[0] != 0);

    __shared__ float  wlds[8 * 64];      // 2 KB: block's 8 weight rows
    __shared__ double e2lds[NEMB];       // 4 KB: candidate squared norms
    __shared__ int    bidx_lds[8];

    if (t < 128)
        reinterpret_cast<float4*>(wlds)[t] =
            reinterpret_cast<const float4*>(weight + (size_t)rblk * 64)[t];

    {   // e2 pre-phase: thread t -> candidates 2t, 2t+1 (float2 coalesced)
        double s0 = 0.0, s1 = 0.0;
        for (int d = 0; d < DQ; ++d) {
            const float2 e = *reinterpret_cast<const float2*>(embed + d * NEMB + 2 * t);
            s0 = fma((double)e.x, (double)e.x, s0);
            s1 = fma((double)e.y, (double)e.y, s1);
        }
        e2lds[2 * t]     = s0;
        e2lds[2 * t + 1] = s1;
    }
    __syncthreads();

    if (qon) {
        const int j0 = lane * 8;         // this lane's 8 contiguous candidates
        const int r0 = wave * 2;         // wave's first local row

        double a0[8], a1[8];
#pragma unroll
        for (int c = 0; c < 8; ++c) { a0[c] = 0.0; a1[c] = 0.0; }

        for (int d = 0; d < DQ; ++d) {
            const float4 ea = *reinterpret_cast<const float4*>(embed + d * NEMB + j0);
            const float4 eb = *reinterpret_cast<const float4*>(embed + d * NEMB + j0 + 4);
            double ev[8];
            ev[0] = (double)ea.x; ev[1] = (double)ea.y; ev[2] = (double)ea.z; ev[3] = (double)ea.w;
            ev[4] = (double)eb.x; ev[5] = (double)eb.y; ev[6] = (double)eb.z; ev[7] = (double)eb.w;
            const double w0 = (double)wlds[r0 * 64 + d];        // LDS broadcast
            const double w1 = (double)wlds[r0 * 64 + 64 + d];
#pragma unroll
            for (int c = 0; c < 8; ++c) a0[c] = fma(w0, ev[c], a0[c]);
#pragma unroll
            for (int c = 0; c < 8; ++c) a1[c] = fma(w1, ev[c], a1[c]);
        }

#pragma unroll
        for (int r = 0; r < 2; ++r) {
            double best = 1e300;
            int bi = 0;
#pragma unroll
            for (int c = 0; c < 8; ++c) {
                const double q = fma(-2.0, (r == 0 ? a0[c] : a1[c]), e2lds[j0 + c]);
                if (q < best) { best = q; bi = j0 + c; }   // ascending j keeps lowest idx
            }
#pragma unroll
            for (int off = 1; off < 64; off <<= 1) {
                const double ob = __shfl_xor(best, off, 64);
                const int    oi = __shfl_xor(bi,   off, 64);
                if (ob < best || (ob == best && oi < bi)) { best = ob; bi = oi; }
            }
            if (lane == 0) bidx_lds[r0 + r] = bi;
        }
    }
    __syncthreads();

    // ---- write phase: 64 threads; thread = (row, om); 16 B coalesced store ----
    float dsum = 0.f;
    if (t < 64) {
        const int rloc = t >> 3, om = t & 7;
        const int row = rblk + rloc;
        const int g = row >> 6, og = row & 63;
        const int bidx = qon ? bidx_lds[rloc] : 0;
        alignas(16) unsigned short q8[8];
#pragma unroll
        for (int i = 0; i < 8; ++i) {
            const int d = i * 8 + om;
            const float wv = wlds[rloc * 64 + d];
            float qv;
            if (qon) {
                qv = embed[d * NEMB + bidx];
                const float df = qv - wv;
                dsum = fmaf(df, df, dsum);
            } else {
                qv = wv;
            }
            q8[i] = f2bf(qv);
        }
        // W[k = g*8+i][n = og*8+om] -> wt[n*KDIM + k]; 8 consecutive k = 16 B
        *reinterpret_cast<int4*>(wt + (size_t)(og * 8 + om) * KDIM + g * 8) =
            *reinterpret_cast<const int4*>(q8);
    }
    if (wave == 0) {                     // only wave 0 holds nonzero dsum
#pragma unroll
        for (int off = 32; off > 0; off >>= 1) dsum += __shfl_down(dsum, off, 64);
        if (lane == 0) partials[bid] = dsum;
    }
}

// ---------------------------------------------------------------------------
// Kernel 2: res = xb[8192,512] @ wt^T   (wt stored [N][K])
// 128x64 tile, BK=64 (8 K-iters -> half the barrier drains), 4 waves (2m x 2n,
// each 64x32). XOR k-chunk swizzle: LDS position of 16 B chunk c in row r is
// (c ^ (r&7)) -- applied on the GLOBAL side of global_load_lds (dest must stay
// wave-contiguous), makes b128 fragment reads bank-conflict-free at 128 B row
// stride. Grid 512 = 2 blocks/CU; swizzle groups 8 m-stripes per XCD.
// ---------------------------------------------------------------------------
__global__ __launch_bounds__(256) void gemm_kernel(
    const unsigned short* __restrict__ xb,   // bf16 [8192][512]
    const unsigned short* __restrict__ wt,   // bf16 [512][512]
    float* __restrict__ out,                 // fp32 [8192][512]
    const float* __restrict__ partials,      // [512]
    float* diff_slot)
{
    __shared__ unsigned short As[128 * 64];  // 16 KB [m][k], xor-swizzled chunks
    __shared__ unsigned short Bs[64 * 64];   //  8 KB [n][k], xor-swizzled chunks

    const int tid  = threadIdx.x;
    const int wave = tid >> 6;
    const int lane = tid & 63;

    // block swizzle: XCD x (= flat&7 heuristic) owns m-tiles [x*8, x*8+8),
    // each with all 8 n-tiles -> A slab L2-resident per XCD.
    const int flat = blockIdx.x;             // 0..511
    const int xcd  = flat & 7;
    const int sub  = flat >> 3;              // 0..63
    const int nt   = sub & 7;
    const int mt   = xcd * 8 + (sub >> 3);   // 0..63
    const int m0 = mt * 128;
    const int n0 = nt * 64;
    const int wm = (wave >> 1) * 64;
    const int wn = (wave & 1) * 32;

    // staging: 8-row group per wave-instr; lane -> (row, swizzled source chunk)
    const int srow   = lane >> 3;            // row within 8-row group
    const int schunk = (lane & 7) ^ srow;    // logical k-chunk feeding LDS slot lane*16
    // fragments
    const int mrow = lane & 15;
    const int cq   = lane >> 4;              // chunk quarter 0..3

    floatx4 acc[4][2] = {};

    for (int k0 = 0; k0 < KDIM; k0 += 64) {
        __syncthreads();
#pragma unroll
        for (int c = 0; c < 4; ++c) {        // A: 16 groups of 8 rows; 4/wave
            const int g = wave * 4 + c;
            const int row = g * 8 + srow;
            async16(xb + (size_t)(m0 + row) * KDIM + k0 + schunk * 8, (char*)As + g * 1024);
        }
#pragma unroll
        for (int c = 0; c < 2; ++c) {        // B: 8 groups; 2/wave
            const int g = wave * 2 + c;
            const int row = g * 8 + srow;
            async16(wt + (size_t)(n0 + row) * KDIM + k0 + schunk * 8, (char*)Bs + g * 1024);
        }
        __syncthreads();

#pragma unroll
        for (int ks = 0; ks < 2; ++ks) {
            bf16x8 a[4], b[2];
#pragma unroll
            for (int i = 0; i < 4; ++i) {
                const int r = wm + i * 16 + mrow;
                const int c = ks * 4 + cq;
                a[i] = *reinterpret_cast<const bf16x8*>(&As[r * 64 + ((c ^ (r & 7)) * 8)]);
            }
#pragma unroll
            for (int j = 0; j < 2; ++j) {
                const int r = wn + j * 16 + mrow;
                const int c = ks * 4 + cq;
                b[j] = *reinterpret_cast<const bf16x8*>(&Bs[r * 64 + ((c ^ (r & 7)) * 8)]);
            }
#pragma unroll
            for (int i = 0; i < 4; ++i)
#pragma unroll
                for (int j = 0; j < 2; ++j)
                    acc[i][j] = __builtin_amdgcn_mfma_f32_16x16x32_bf16(a[i], b[j], acc[i][j], 0, 0, 0);
        }
    }

    // C/D layout: col = lane&15, row = (lane>>4)*4 + reg  (m89-verified)
    const int col = lane & 15;
    const int rbase = (lane >> 4) * 4;
#pragma unroll
    for (int i = 0; i < 4; ++i)
#pragma unroll
        for (int j = 0; j < 2; ++j)
#pragma unroll
            for (int r = 0; r < 4; ++r) {
                const int mm = m0 + wm + i * 16 + rbase + r;
                const int nn = n0 + wn + j * 16 + col;
                out[(size_t)mm * NDIM + nn] = acc[i][j][r];
            }

    // diff reduction (one wave of one block)
    if (flat == 0 && wave == 0 && diff_slot) {
        float s = 0.f;
#pragma unroll
        for (int q = 0; q < 8; ++q) s += partials[lane + 64 * q];
#pragma unroll
        for (int off = 32; off > 0; off >>= 1) s += __shfl_down(s, off, 64);
        if (lane == 0) diff_slot[0] = s * (1.f / (NROWS * DQ));
    }
}

// ---------------------------------------------------------------------------
extern "C" void kernel_launch(void* const* d_in, const int* in_sizes, int n_in,
                              void* d_out, int out_size, void* d_ws, size_t ws_size,
                              hipStream_t stream)
{
    const float* x      = (const float*)d_in[0];
    const float* weight = (const float*)d_in[1];
    const float* embed  = (const float*)d_in[2];
    const int*   use_qw = (const int*)d_in[3];
    float* out = (float*)d_out;

    // ws layout: [0,512K) W^T bf16 ; [512K,514K) diff partials ; [1M,9M) x bf16
    unsigned short* wt = (unsigned short*)d_ws;
    float* partials    = (float*)((char*)d_ws + (512u << 10));
    unsigned short* xb = (unsigned short*)((char*)d_ws + (1u << 20));

    float* diff_slot = (out_size > BATCH * NDIM) ? (out + (size_t)BATCH * NDIM) : nullptr;

    fused_prep_vq<<<VQ_BLOCKS + CONV_BLOCKS, 256, 0, stream>>>(
        x, weight, embed, xb, wt, partials, use_qw);
    gemm_kernel<<<512, 256, 0, stream>>>(xb, wt, out, partials, diff_slot);
}